// Round 2
// baseline (283.364 us; speedup 1.0000x reference)
//
#include <hip/hip_runtime.h>

// ---------------------------------------------------------------------------
// SelfAttention: out = softmax((x@Wk+bk) @ (x@Wq+bq)^T) @ (x@Wv+bv)
// B=4, N=2048, E=A=1024, fp32 in/out.
// R10: delivery-side fixes (R9 post-mortem: GEMMs are operand-delivery-bound,
// FETCH=79MB vs 22MB compulsory -> L2 thrash across XCDs):
//  - T1 XCD-chunked bijective blockIdx swizzle (m157) on all GEMMs.
//  - gemm8p: fragment ds_reads moved AFTER previous phase's MFMA (read-ahead
//    by one phase); P4 MFMA is pure-register under the deep vmcnt(6) wait.
//  - hoisted LDS swizzle offsets (r&7==l15&7 for all fragment rows).
//  - accumulation order identical to R8/R9 -> bit-identical numerics.
// ---------------------------------------------------------------------------

typedef __attribute__((ext_vector_type(8))) _Float16 half8;   // 4 VGPRs
typedef __attribute__((ext_vector_type(4))) float floatx4;

#define BK 64

#define BARRIER() asm volatile("s_barrier" ::: "memory")
#define WAITV(n)  asm volatile("s_waitcnt vmcnt(" #n ")" ::: "memory")
#define WAITL0()  asm volatile("s_waitcnt lgkmcnt(0)" ::: "memory")
#define MFMA16    __builtin_amdgcn_mfma_f32_16x16x32_f16

static __device__ __forceinline__ unsigned short f2h(float f) {
    _Float16 h = (_Float16)f;          // RNE
    return *(unsigned short*)&h;
}

// async global->LDS, 16B per lane; LDS dst = wave-uniform base + lane*16
static __device__ __forceinline__ void gll16(const unsigned short* g,
                                             unsigned short* l) {
    __builtin_amdgcn_global_load_lds(
        (__attribute__((address_space(1))) void*)(g),
        (__attribute__((address_space(3))) void*)(l), 16, 0, 0);
}

// XCD-chunked bijective remap (m157 formula; requires nwg % 8 == 0, true for
// all GEMM grids here: 384 / 256 / 512). Consecutive work ids land on ONE
// XCD -> operand panels stay resident in that XCD's L2.
static __device__ __forceinline__ void xcd_remap(int& bx, int& by, int& bz) {
    const int gx = gridDim.x, gy = gridDim.y, gz = gridDim.z;
    const int flat = blockIdx.x + gx * (blockIdx.y + gy * blockIdx.z);
    const int w = (flat & 7) * ((gx * gy * gz) >> 3) + (flat >> 3);
    bx = w % gx;
    const int r = w / gx;
    by = r % gy;
    bz = r / gy;
}

// ---------------------------------------------------------------------------
// prep: blocks 0..8191 cast x -> fp16; 8192..11263 transpose W0..2 -> fp16;
// 11264..11275 bias concat.
// ---------------------------------------------------------------------------
__global__ __launch_bounds__(256)
void prep(const float* __restrict__ x,
          const float* __restrict__ W0, const float* __restrict__ W1,
          const float* __restrict__ W2,
          const float* __restrict__ b0, const float* __restrict__ b1,
          const float* __restrict__ b2,
          unsigned short* __restrict__ x16, unsigned short* __restrict__ WT,
          float* __restrict__ bias3) {
    __shared__ float tile[32][33];
    const int bid = blockIdx.x;
    if (bid < 8192) {
        int i = bid * 1024 + threadIdx.x * 4;
        float4 f = *(const float4*)(x + i);
        *(ushort4*)(x16 + i) =
            make_ushort4(f2h(f.x), f2h(f.y), f2h(f.z), f2h(f.w));
    } else if (bid < 11264) {
        int wz = bid - 8192;
        int z = wz >> 10;
        int t = wz & 1023;
        const float* W = z == 0 ? W0 : (z == 1 ? W1 : W2);
        unsigned short* Tz = WT + (size_t)z * 1024 * 1024;
        int c0 = (t & 31) * 32, r0 = (t >> 5) * 32;
        int tx = threadIdx.x & 31, ty = threadIdx.x >> 5;
#pragma unroll
        for (int j = 0; j < 32; j += 8)
            tile[ty + j][tx] = W[(r0 + ty + j) * 1024 + c0 + tx];
        __syncthreads();
#pragma unroll
        for (int j = 0; j < 32; j += 8)
            Tz[(c0 + ty + j) * 1024 + r0 + tx] = f2h(tile[tx][ty + j]);
    } else {
        int i = (bid - 11264) * 256 + threadIdx.x;
        int s = i >> 10;
        const float* b = s == 0 ? b0 : (s == 1 ? b1 : b2);
        bias3[i] = b[i & 1023];
    }
}

// ---------------------------------------------------------------------------
// Half-tile stager for the 8-phase kernel (unchanged, verified R9).
// RBL=6: A halves (two 64-row blocks at stride 128); RBL=5: B halves.
// ---------------------------------------------------------------------------
template <int RBL>
static __device__ __forceinline__ void stage_half(
    const unsigned short* __restrict__ G, unsigned short* lds, int off,
    int K, int tid) {
#pragma unroll
    for (int j = 0; j < 2; ++j) {
        const int li  = j * 64 + (tid >> 3);
        const int li0 = j * 64 + ((tid >> 6) << 3);      // wave lane-0 slot
        const int r   = ((li  >> RBL) << (RBL + 1)) + off + (li  & ((1 << RBL) - 1));
        const int r0  = ((li0 >> RBL) << (RBL + 1)) + off + (li0 & ((1 << RBL) - 1));
        const int kc  = (((tid & 7) ^ (r & 7)) << 3);
        gll16(G + (long long)r * K + kc, lds + r0 * 64);
    }
}

// ---------------------------------------------------------------------------
// 8-phase NT GEMM: C[M,N] = A[M,K] * B[N,K]^T (+bias[col]); fp16 in, f32 acc.
// Block 256x256, 512 threads (8 waves 2Mx4N), BK=64, LDS 2x(256+256)x64 fp16.
// Read-ahead schedule: phase p's fragment ds_reads issue after phase p-1's
// MFMA; P4's MFMA is pure-register and covers the vmcnt(6) wait + the
// 12-read reload for the next tile.
// ---------------------------------------------------------------------------
__global__ __launch_bounds__(512, 2)
void gemm8p(const unsigned short* __restrict__ A,
            const unsigned short* __restrict__ B,
            const float* __restrict__ bias,
            float* __restrict__ Cf,
            unsigned short* __restrict__ Ch,
            int mode, int N, int K,
            long long sA, long long sB, long long sC) {
    __shared__ unsigned short smem[2][512 * BK];   // [buf][A(256)+B(256)][64]

    const int tid  = threadIdx.x;
    const int lane = tid & 63;
    const int wave = tid >> 6;            // 0..7
    const int quad = lane >> 4;
    const int l15  = lane & 15;
    const int wm   = (wave & 1) * 128;    // wave M offset
    const int wn   = (wave >> 1) * 64;    // wave N offset
    // every fragment row r has r&7 == l15&7 -> one hoisted swizzle offset.
    const int swz0 = (quad ^ (l15 & 7)) << 3;   // shorts; tt=1 offset = ^32

    int bx, by, bz;
    xcd_remap(bx, by, bz);
    const int m0 = by * 256;
    const int n0 = bx * 256;
    const unsigned short* Ag = A + (long long)bz * sA + (long long)m0 * K;
    const unsigned short* Bg = B + (long long)bz * sB + (long long)n0 * K;
    const int NT = K >> 6;

#define S_ALO(b, t) stage_half<6>(Ag + (t) * BK, smem[b],            0,  K, tid)
#define S_AHI(b, t) stage_half<6>(Ag + (t) * BK, smem[b],            64, K, tid)
#define S_BLO(b, t) stage_half<5>(Bg + (t) * BK, smem[b] + 256 * BK, 0,  K, tid)
#define S_BHI(b, t) stage_half<5>(Bg + (t) * BK, smem[b] + 256 * BK, 32, K, tid)

#define LD_ALO(b)                                                            \
    _Pragma("unroll") for (int mi = 0; mi < 4; ++mi)                         \
        _Pragma("unroll") for (int tt = 0; tt < 2; ++tt)                     \
            aLo[mi][tt] = *(const half8*)&smem[b][                           \
                (wm + mi * 16 + l15) * 64 + (swz0 ^ (tt * 32))];
#define LD_AHI(b)                                                            \
    _Pragma("unroll") for (int mi = 0; mi < 4; ++mi)                         \
        _Pragma("unroll") for (int tt = 0; tt < 2; ++tt)                     \
            aHi[mi][tt] = *(const half8*)&smem[b][                           \
                (wm + 64 + mi * 16 + l15) * 64 + (swz0 ^ (tt * 32))];
#define LD_BLO(b)                                                            \
    _Pragma("unroll") for (int ni = 0; ni < 2; ++ni)                         \
        _Pragma("unroll") for (int tt = 0; tt < 2; ++tt)                     \
            bLo[ni][tt] = *(const half8*)&smem[b][256 * BK +                 \
                (wn + ni * 16 + l15) * 64 + (swz0 ^ (tt * 32))];
#define LD_BHI(b)                                                            \
    _Pragma("unroll") for (int ni = 0; ni < 2; ++ni)                         \
        _Pragma("unroll") for (int tt = 0; tt < 2; ++tt)                     \
            bHi[ni][tt] = *(const half8*)&smem[b][256 * BK +                 \
                (wn + 32 + ni * 16 + l15) * 64 + (swz0 ^ (tt * 32))];

#define MQ(AF, BF, MO, NO)                                                   \
    __builtin_amdgcn_s_setprio(1);                                           \
    _Pragma("unroll") for (int tt = 0; tt < 2; ++tt)                         \
        _Pragma("unroll") for (int mi = 0; mi < 4; ++mi)                     \
            _Pragma("unroll") for (int ni = 0; ni < 2; ++ni)                 \
                acc[MO + mi][NO + ni] = MFMA16(AF[mi][tt], BF[ni][tt],       \
                                               acc[MO + mi][NO + ni], 0, 0, 0); \
    __builtin_amdgcn_s_setprio(0);

    floatx4 zero = {0.f, 0.f, 0.f, 0.f};
    floatx4 acc[8][4];
#pragma unroll
    for (int i = 0; i < 8; ++i)
#pragma unroll
        for (int j = 0; j < 4; ++j) acc[i][j] = zero;

    half8 aLo[4][2], aHi[4][2], bLo[2][2], bHi[2][2];

    // prologue: prime pipeline. After WAITV(6): {Blo0,Alo0,Bhi0} landed;
    // {Ahi0,Blo1,Alo1} in flight (Ahi0 lands at t=0.P2's vmcnt(8)).
    S_BLO(0, 0); S_ALO(0, 0); S_BHI(0, 0);
    S_AHI(0, 0); S_BLO(1, 1); S_ALO(1, 1);
    WAITV(6);
    BARRIER();
    LD_ALO(0);
    LD_BLO(0);

    int cur = 0;
    for (int t = 0; t < NT; ++t, cur ^= 1) {
        // ---- P1: MFMA Q(lo,lo) [regs from prev P4]; stage (t+1).Bhi ----
        if (t + 1 < NT) S_BHI(cur ^ 1, t + 1);
        BARRIER();
        WAITL0();                       // drains aLo/bLo reads
        MQ(aLo, bLo, 0, 0);
        LD_BHI(cur);                    // 4 reads for P2
        BARRIER();

        // ---- P2: MFMA Q(lo,hi); stage (t+1).Ahi; vmcnt(8) lands Ahi(t) ----
        if (t + 1 < NT) S_AHI(cur ^ 1, t + 1);
        WAITV(8);
        BARRIER();
        WAITL0();                       // drains bHi reads
        MQ(aLo, bHi, 0, 2);
        LD_AHI(cur);                    // 8 reads for P3/P4 (Ahi(t) landed)
        BARRIER();

        // ---- P3: MFMA Q(hi,hi); stage (t+2).Blo -> cur buf ----
        if (t + 2 < NT) S_BLO(cur, t + 2);
        BARRIER();
        WAITL0();                       // drains aHi reads
        MQ(aHi, bHi, 4, 2);
        BARRIER();

        // ---- P4: MFMA Q(hi,lo) pure-reg; stage (t+2).Alo; vmcnt(6)
        //      lands {Blo,Alo,Bhi}(t+1); reload aLo/bLo for next tile ----
        if (t + 2 < NT) S_ALO(cur, t + 2);
        if (t == NT - 2) { WAITV(0); } else { WAITV(6); }   // tail drain once
        BARRIER();
        MQ(aHi, bLo, 4, 0);
        if (t + 1 < NT) {
            LD_ALO(cur ^ 1);            // 12 reads for next tile's P1
            LD_BLO(cur ^ 1);
        }
        BARRIER();
    }

    // epilogue: C/D layout col=lane&15, row=quad*4+reg  [verified m89/m91]
#pragma unroll
    for (int mi = 0; mi < 8; ++mi)
#pragma unroll
        for (int ni = 0; ni < 4; ++ni) {
            int colg = n0 + wn + ni * 16 + l15;
            float bv = bias ? bias[colg] : 0.f;
#pragma unroll
            for (int r = 0; r < 4; ++r) {
                int rowg = m0 + wm + mi * 16 + quad * 4 + r;
                float v = acc[mi][ni][r] + bv;
                if (mode == 0) {
                    Cf[(long long)bz * sC + (long long)rowg * N + colg] = v;
                } else {  // mode 2: segmented fp16 (k16|q16|v16 contiguous)
                    int seg = colg >> 10;
                    Ch[(long long)seg * sC + (long long)rowg * 1024 +
                       (colg & 1023)] = f2h(v);
                }
            }
        }
#undef S_ALO
#undef S_AHI
#undef S_BLO
#undef S_BHI
#undef LD_ALO
#undef LD_AHI
#undef LD_BLO
#undef LD_BHI
#undef MQ
}

// ---------------------------------------------------------------------------
// NT GEMM (2-barrier structure) — retained for PV (256^2 grid too small).
// R10: + XCD remap.
// ---------------------------------------------------------------------------
template <int TM>
__global__ __launch_bounds__(256, 2)
void gemm_nt(const unsigned short* __restrict__ A,
             const unsigned short* __restrict__ B,
             const float* __restrict__ bias,
             float* __restrict__ Cf,
             unsigned short* __restrict__ Ch,
             int mode, int M, int N, int K,
             long long sA, long long sB, long long sC) {
    constexpr int WM = TM / 2;
    constexpr int MI = WM / 16;
    __shared__ unsigned short smem[(TM + 128) * BK];
    unsigned short* As = smem;
    unsigned short* Bs = smem + TM * BK;

    const int tid = threadIdx.x;
    const int lane = tid & 63;
    const int wave = tid >> 6;
    const int quad = lane >> 4;
    const int l15 = lane & 15;
    const int wm = (wave & 1) * WM;
    const int wn = (wave >> 1) * 64;

    int bx, by, bz;
    xcd_remap(bx, by, bz);
    const long long zA = (long long)bz * sA;
    const long long zB = (long long)bz * sB;
    const long long zC = (long long)bz * sC;
    const int m0 = by * TM;
    const int n0 = bx * 128;

    const int arow = wave * (TM / 4) + (lane >> 3);
    const int brow = wave * 32 + (lane >> 3);
    const int schunk8 = (((lane & 7) ^ ((lane >> 3) & 7)) << 3);
    const long long aoff = zA + (long long)(m0 + arow) * K + schunk8;
    const long long boff = zB + (long long)(n0 + brow) * K + schunk8;
    unsigned short* lA = As + (wave * (TM / 4)) * BK;
    unsigned short* lB = Bs + (wave * 32) * BK;

    floatx4 zero = {0.f, 0.f, 0.f, 0.f};
    floatx4 acc[MI][4];
#pragma unroll
    for (int i = 0; i < MI; ++i)
#pragma unroll
        for (int j = 0; j < 4; ++j) acc[i][j] = zero;

    for (int k0 = 0; k0 < K; k0 += BK) {
        __syncthreads();
#pragma unroll
        for (int j = 0; j < TM / 32; ++j)
            gll16(A + aoff + k0 + (long long)j * 8 * K, lA + j * 8 * BK);
#pragma unroll
        for (int j = 0; j < 4; ++j)
            gll16(B + boff + k0 + (long long)j * 8 * K, lB + j * 8 * BK);
        __syncthreads();

#pragma unroll
        for (int t = 0; t < 2; ++t) {
            half8 a[MI], b[4];
#pragma unroll
            for (int mi = 0; mi < MI; ++mi) {
                int r = wm + mi * 16 + l15;
                int p = (t * 4 + quad) ^ (r & 7);
                a[mi] = *(const half8*)&As[r * BK + p * 8];
            }
#pragma unroll
            for (int ni = 0; ni < 4; ++ni) {
                int r = wn + ni * 16 + l15;
                int p = (t * 4 + quad) ^ (r & 7);
                b[ni] = *(const half8*)&Bs[r * BK + p * 8];
            }
#pragma unroll
            for (int mi = 0; mi < MI; ++mi)
#pragma unroll
                for (int ni = 0; ni < 4; ++ni)
                    acc[mi][ni] = MFMA16(a[mi], b[ni], acc[mi][ni], 0, 0, 0);
        }
    }

#pragma unroll
    for (int mi = 0; mi < MI; ++mi)
#pragma unroll
        for (int ni = 0; ni < 4; ++ni) {
            int colg = n0 + wn + ni * 16 + l15;
            float bv = bias ? bias[colg] : 0.f;
#pragma unroll
            for (int r = 0; r < 4; ++r) {
                int rowg = m0 + wm + mi * 16 + quad * 4 + r;
                float v = acc[mi][ni][r] + bv;
                if (mode == 0) {
                    Cf[zC + (long long)rowg * N + colg] = v;
                } else {
                    int seg = colg >> 10;
                    Ch[(long long)seg * sC + (long long)rowg * 1024 +
                       (colg & 1023)] = f2h(v);
                }
            }
        }
}

// ---------------------------------------------------------------------------
// fused: blocks 0..8191 = row softmax; 8192..16383 = v16 -> vT transpose
// ---------------------------------------------------------------------------
__global__ __launch_bounds__(256)
void softmax_vT(const float* __restrict__ S, unsigned short* __restrict__ P,
                const unsigned short* __restrict__ v,
                unsigned short* __restrict__ vT) {
    __shared__ float red_m[4];
    __shared__ float red_s[4];
    __shared__ unsigned short tile[32][33];
    const int bid = blockIdx.x;
    const int tid = threadIdx.x;

    if (bid < 8192) {
        const float* s = S + (long long)bid * 2048;
        unsigned short* p = P + (long long)bid * 2048;
        const int lane = tid & 63;
        const int wave = tid >> 6;

        float4 v0 = *(const float4*)(s + tid * 8);
        float4 v1 = *(const float4*)(s + tid * 8 + 4);
        float vals[8] = {v0.x, v0.y, v0.z, v0.w, v1.x, v1.y, v1.z, v1.w};

        float m = vals[0];
#pragma unroll
        for (int i = 1; i < 8; ++i) m = fmaxf(m, vals[i]);
#pragma unroll
        for (int off = 32; off >= 1; off >>= 1)
            m = fmaxf(m, __shfl_xor(m, off));
        if (lane == 0) red_m[wave] = m;
        __syncthreads();
        m = fmaxf(fmaxf(red_m[0], red_m[1]), fmaxf(red_m[2], red_m[3]));

        float e[8];
        float sum = 0.f;
#pragma unroll
        for (int i = 0; i < 8; ++i) {
            e[i] = __expf(vals[i] - m);
            sum += e[i];
        }
#pragma unroll
        for (int off = 32; off >= 1; off >>= 1) sum += __shfl_xor(sum, off);
        if (lane == 0) red_s[wave] = sum;
        __syncthreads();
        sum = red_s[0] + red_s[1] + red_s[2] + red_s[3];
        float inv = 1.0f / sum;

        unsigned short ob[8];
#pragma unroll
        for (int i = 0; i < 8; ++i) ob[i] = f2h(e[i] * inv);
        *(ushort4*)(p + tid * 8)     = make_ushort4(ob[0], ob[1], ob[2], ob[3]);
        *(ushort4*)(p + tid * 8 + 4) = make_ushort4(ob[4], ob[5], ob[6], ob[7]);
    } else {
        int t = bid - 8192;
        int z = t >> 11;
        int rest = t & 2047;
        int c0 = (rest & 31) * 32;
        int r0 = (rest >> 5) * 32;
        long long zs = (long long)z * 2048 * 1024;
        int tx = tid & 31, ty = tid >> 5;
#pragma unroll
        for (int j = 0; j < 32; j += 8)
            tile[ty + j][tx] = v[zs + (long long)(r0 + ty + j) * 1024 + c0 + tx];
        __syncthreads();
#pragma unroll
        for (int j = 0; j < 32; j += 8)
            vT[zs + (long long)(c0 + ty + j) * 2048 + r0 + tx] =
                tile[tx][ty + j];
    }
}

// ---------------------------------------------------------------------------
extern "C" void kernel_launch(void* const* d_in, const int* in_sizes, int n_in,
                              void* d_out, int out_size, void* d_ws,
                              size_t ws_size, hipStream_t stream) {
    const float* x  = (const float*)d_in[0];
    const float* Wk = (const float*)d_in[1];
    const float* bk = (const float*)d_in[2];
    const float* Wq = (const float*)d_in[3];
    const float* bq = (const float*)d_in[4];
    const float* Wv = (const float*)d_in[5];
    const float* bv = (const float*)d_in[6];
    float* out = (float*)d_out;

    const int Bb = 4, Ns = 2048, E = 1024, Aa = 1024;
    const int M = Bb * Ns;  // 8192

    char* p = (char*)d_ws;
    auto alloc = [&](size_t bytes) {
        char* r = p;
        p += (bytes + 255) & ~(size_t)255;
        return r;
    };
    const size_t MA = (size_t)M * Aa;
    unsigned short* x16 = (unsigned short*)alloc(MA * 2);
    unsigned short* WT  = (unsigned short*)alloc((size_t)3 * E * Aa * 2);
    unsigned short* k16 = (unsigned short*)alloc(MA * 2);
    unsigned short* q16 = (unsigned short*)alloc(MA * 2);
    unsigned short* v16 = (unsigned short*)alloc(MA * 2);
    unsigned short* vT  = (unsigned short*)alloc(MA * 2);
    unsigned short* attn = (unsigned short*)alloc((size_t)M * Ns * 2);
    float* bias3 = (float*)alloc(3072 * 4);
    float* scores = (float*)alloc((size_t)Bb * Ns * Ns * 4);

    // 1. prep: x->fp16, W^T x3, bias concat
    prep<<<11276, 256, 0, stream>>>(x, Wk, Wq, Wv, bk, bq, bv, x16, WT, bias3);

    // 2. fused projections (8-phase): [k|q|v] = x16 @ [Wk|Wq|Wv]^T + bias3
    gemm8p<<<dim3(3 * Aa / 256, M / 256, 1), 512, 0, stream>>>(
        x16, WT, bias3, nullptr, k16, 2, 3 * Aa, E, 0, 0, (long long)MA);

    // 3. scores[b,n,m] = k[b,n,:] . q[b,m,:]  (8-phase, fp32 out)
    gemm8p<<<dim3(Ns / 256, Ns / 256, Bb), 512, 0, stream>>>(
        k16, q16, nullptr, scores, nullptr, 0, Ns, Aa,
        (long long)Ns * Aa, (long long)Ns * Aa, (long long)Ns * Ns);

    // 4. softmax rows -> fp16 attn; v -> v^T
    softmax_vT<<<16384, 256, 0, stream>>>(scores, attn, v16, vT);

    // 5. out[b,n,a] = sum_m attn[b,n,m] * vT[b,a,m]
    gemm_nt<128><<<dim3(Aa / 128, Ns / 128, Bb), 256, 0, stream>>>(
        attn, vT, nullptr, out, nullptr, 0, Ns, Aa, Ns,
        (long long)Ns * Ns, (long long)Aa * Ns, (long long)Ns * Aa);
}

// Round 3
// 266.871 us; speedup vs baseline: 1.0618x; 1.0618x over previous
//
#include <hip/hip_runtime.h>

// ---------------------------------------------------------------------------
// SelfAttention: out = softmax((x@Wk+bk) @ (x@Wq+bq)^T) @ (x@Wv+bv)
// B=4, N=2048, E=A=1024, fp32 in/out.
// R11: revert to R8's 2-barrier gemm_nt (8-phase was 25% MfmaUtil both
// variants, below R8). Changes vs R8:
//  - TM=128 for ALL GEMMs (m112: 912 vs 792 TF favors 128^2 at this
//    structure; 32KB LDS -> 5 blocks/CU -> inter-block overlap hides the
//    single-buffer vmcnt(0) drain; grids 1536/1024/512 all %256==0, no
//    tail-round waste).
//  - XCD-chunked bijective blockIdx swizzle kept (R10: FETCH -22%).
//  - accumulation order unchanged -> absmax bit-identical (0.08105469).
// ---------------------------------------------------------------------------

typedef __attribute__((ext_vector_type(8))) _Float16 half8;   // 4 VGPRs
typedef __attribute__((ext_vector_type(4))) float floatx4;

#define BK 64
#define MFMA16 __builtin_amdgcn_mfma_f32_16x16x32_f16

static __device__ __forceinline__ unsigned short f2h(float f) {
    _Float16 h = (_Float16)f;          // RNE
    return *(unsigned short*)&h;
}

// async global->LDS, 16B per lane; LDS dst = wave-uniform base + lane*16
static __device__ __forceinline__ void gll16(const unsigned short* g,
                                             unsigned short* l) {
    __builtin_amdgcn_global_load_lds(
        (__attribute__((address_space(1))) void*)(g),
        (__attribute__((address_space(3))) void*)(l), 16, 0, 0);
}

// XCD-chunked bijective remap (m157; requires nwg % 8 == 0 — grids here are
// 1536 / 1024 / 512). Consecutive work ids land on ONE XCD -> operand panels
// stay resident in that XCD's L2. [R10: FETCH 79->62 MB on proj]
static __device__ __forceinline__ void xcd_remap(int& bx, int& by, int& bz) {
    const int gx = gridDim.x, gy = gridDim.y, gz = gridDim.z;
    const int flat = blockIdx.x + gx * (blockIdx.y + gy * blockIdx.z);
    const int w = (flat & 7) * ((gx * gy * gz) >> 3) + (flat >> 3);
    bx = w % gx;
    const int r = w / gx;
    by = r % gy;
    bz = r / gy;
}

// ---------------------------------------------------------------------------
// prep: blocks 0..8191 cast x -> fp16; 8192..11263 transpose W0..2 -> fp16;
// 11264..11275 bias concat.
// ---------------------------------------------------------------------------
__global__ __launch_bounds__(256)
void prep(const float* __restrict__ x,
          const float* __restrict__ W0, const float* __restrict__ W1,
          const float* __restrict__ W2,
          const float* __restrict__ b0, const float* __restrict__ b1,
          const float* __restrict__ b2,
          unsigned short* __restrict__ x16, unsigned short* __restrict__ WT,
          float* __restrict__ bias3) {
    __shared__ float tile[32][33];
    const int bid = blockIdx.x;
    if (bid < 8192) {
        int i = bid * 1024 + threadIdx.x * 4;
        float4 f = *(const float4*)(x + i);
        *(ushort4*)(x16 + i) =
            make_ushort4(f2h(f.x), f2h(f.y), f2h(f.z), f2h(f.w));
    } else if (bid < 11264) {
        int wz = bid - 8192;
        int z = wz >> 10;
        int t = wz & 1023;
        const float* W = z == 0 ? W0 : (z == 1 ? W1 : W2);
        unsigned short* Tz = WT + (size_t)z * 1024 * 1024;
        int c0 = (t & 31) * 32, r0 = (t >> 5) * 32;
        int tx = threadIdx.x & 31, ty = threadIdx.x >> 5;
#pragma unroll
        for (int j = 0; j < 32; j += 8)
            tile[ty + j][tx] = W[(r0 + ty + j) * 1024 + c0 + tx];
        __syncthreads();
#pragma unroll
        for (int j = 0; j < 32; j += 8)
            Tz[(c0 + ty + j) * 1024 + r0 + tx] = f2h(tile[tx][ty + j]);
    } else {
        int i = (bid - 11264) * 256 + threadIdx.x;
        int s = i >> 10;
        const float* b = s == 0 ? b0 : (s == 1 ? b1 : b2);
        bias3[i] = b[i & 1023];
    }
}

// ---------------------------------------------------------------------------
// NT GEMM: C[M,N] = A[M,K] * B[N,K]^T (+bias[col]); fp16 in, fp32 acc.
// Block TM x 128, 256 threads (4 waves, 2x2; wave tile TM/2 x 64), BK=64.
// TM=128: 32KB LDS -> 5 blocks/CU; single-buffered K-loop's vmcnt(0) drain
// is hidden by other resident blocks (poor man's pipeline).
// mode 0: fp32 -> Cf[rowg*N+colg]; mode 2: fp16 segmented -> Ch with
//   segment = colg>>10, Ch[seg*sC + rowg*1024 + (colg&1023)].
// LDS: unpadded [row][64] tiles; XOR chunk swizzle (position p of row r
// holds global chunk p ^ (r&7)) -- conflict-free, verified rocprof (0).
// ---------------------------------------------------------------------------
template <int TM>
__global__ __launch_bounds__(256, 2)
void gemm_nt(const unsigned short* __restrict__ A,
             const unsigned short* __restrict__ B,
             const float* __restrict__ bias,
             float* __restrict__ Cf,
             unsigned short* __restrict__ Ch,
             int mode, int M, int N, int K,
             long long sA, long long sB, long long sC) {
    constexpr int WM = TM / 2;       // wave tile rows
    constexpr int MI = WM / 16;      // acc row-tiles per wave
    __shared__ unsigned short smem[(TM + 128) * BK];
    unsigned short* As = smem;                  // TM x BK
    unsigned short* Bs = smem + TM * BK;        // 128 x BK

    const int tid = threadIdx.x;
    const int lane = tid & 63;
    const int wave = tid >> 6;          // 0..3
    const int quad = lane >> 4;
    const int l15 = lane & 15;
    const int wm = (wave & 1) * WM;
    const int wn = (wave >> 1) * 64;

    int bx, by, bz;
    xcd_remap(bx, by, bz);
    const long long zA = (long long)bz * sA;
    const long long zB = (long long)bz * sB;
    const long long zC = (long long)bz * sC;
    const int m0 = by * TM;
    const int n0 = bx * 128;

    // staging: lane i covers row i>>3; position p=i&7 gets chunk p ^ (row&7)
    const int arow = wave * (TM / 4) + (lane >> 3);
    const int brow = wave * 32 + (lane >> 3);
    const int schunk8 = (((lane & 7) ^ ((lane >> 3) & 7)) << 3);
    const long long aoff = zA + (long long)(m0 + arow) * K + schunk8;
    const long long boff = zB + (long long)(n0 + brow) * K + schunk8;
    unsigned short* lA = As + (wave * (TM / 4)) * BK;
    unsigned short* lB = Bs + (wave * 32) * BK;

    floatx4 zero = {0.f, 0.f, 0.f, 0.f};
    floatx4 acc[MI][4];
#pragma unroll
    for (int i = 0; i < MI; ++i)
#pragma unroll
        for (int j = 0; j < 4; ++j) acc[i][j] = zero;

    for (int k0 = 0; k0 < K; k0 += BK) {
        __syncthreads();
#pragma unroll
        for (int j = 0; j < TM / 32; ++j)
            gll16(A + aoff + k0 + (long long)j * 8 * K, lA + j * 8 * BK);
#pragma unroll
        for (int j = 0; j < 4; ++j)
            gll16(B + boff + k0 + (long long)j * 8 * K, lB + j * 8 * BK);
        __syncthreads();

#pragma unroll
        for (int t = 0; t < 2; ++t) {      // two K=32 MFMA steps per BK=64
            half8 a[MI], b[4];
#pragma unroll
            for (int mi = 0; mi < MI; ++mi) {
                int r = wm + mi * 16 + l15;
                int p = (t * 4 + quad) ^ (r & 7);
                a[mi] = *(const half8*)&As[r * BK + p * 8];
            }
#pragma unroll
            for (int ni = 0; ni < 4; ++ni) {
                int r = wn + ni * 16 + l15;
                int p = (t * 4 + quad) ^ (r & 7);
                b[ni] = *(const half8*)&Bs[r * BK + p * 8];
            }
#pragma unroll
            for (int mi = 0; mi < MI; ++mi)
#pragma unroll
                for (int ni = 0; ni < 4; ++ni)
                    acc[mi][ni] = MFMA16(a[mi], b[ni], acc[mi][ni], 0, 0, 0);
        }
    }

    // epilogue: C/D layout col=lane&15, row=quad*4+reg  [verified m89/m91]
#pragma unroll
    for (int mi = 0; mi < MI; ++mi)
#pragma unroll
        for (int ni = 0; ni < 4; ++ni) {
            int colg = n0 + wn + ni * 16 + l15;
            float bv = bias ? bias[colg] : 0.f;
#pragma unroll
            for (int r = 0; r < 4; ++r) {
                int rowg = m0 + wm + mi * 16 + quad * 4 + r;
                float v = acc[mi][ni][r] + bv;
                if (mode == 0) {
                    Cf[zC + (long long)rowg * N + colg] = v;
                } else {  // mode 2: segmented fp16 (k16|q16|v16 contiguous)
                    int seg = colg >> 10;
                    Ch[(long long)seg * sC + (long long)rowg * 1024 +
                       (colg & 1023)] = f2h(v);
                }
            }
        }
}

// ---------------------------------------------------------------------------
// fused: blocks 0..8191 = row softmax (scores fp32 [8192][2048] -> attn fp16)
//        blocks 8192..16383 = v16 [z][2048][1024] -> vT [z][1024][2048]
// ---------------------------------------------------------------------------
__global__ __launch_bounds__(256)
void softmax_vT(const float* __restrict__ S, unsigned short* __restrict__ P,
                const unsigned short* __restrict__ v,
                unsigned short* __restrict__ vT) {
    __shared__ float red_m[4];
    __shared__ float red_s[4];
    __shared__ unsigned short tile[32][33];
    const int bid = blockIdx.x;
    const int tid = threadIdx.x;

    if (bid < 8192) {
        const float* s = S + (long long)bid * 2048;
        unsigned short* p = P + (long long)bid * 2048;
        const int lane = tid & 63;
        const int wave = tid >> 6;

        float4 v0 = *(const float4*)(s + tid * 8);
        float4 v1 = *(const float4*)(s + tid * 8 + 4);
        float vals[8] = {v0.x, v0.y, v0.z, v0.w, v1.x, v1.y, v1.z, v1.w};

        float m = vals[0];
#pragma unroll
        for (int i = 1; i < 8; ++i) m = fmaxf(m, vals[i]);
#pragma unroll
        for (int off = 32; off >= 1; off >>= 1)
            m = fmaxf(m, __shfl_xor(m, off));
        if (lane == 0) red_m[wave] = m;
        __syncthreads();
        m = fmaxf(fmaxf(red_m[0], red_m[1]), fmaxf(red_m[2], red_m[3]));

        float e[8];
        float sum = 0.f;
#pragma unroll
        for (int i = 0; i < 8; ++i) {
            e[i] = __expf(vals[i] - m);
            sum += e[i];
        }
#pragma unroll
        for (int off = 32; off >= 1; off >>= 1) sum += __shfl_xor(sum, off);
        if (lane == 0) red_s[wave] = sum;
        __syncthreads();
        sum = red_s[0] + red_s[1] + red_s[2] + red_s[3];
        float inv = 1.0f / sum;

        unsigned short ob[8];
#pragma unroll
        for (int i = 0; i < 8; ++i) ob[i] = f2h(e[i] * inv);
        *(ushort4*)(p + tid * 8)     = make_ushort4(ob[0], ob[1], ob[2], ob[3]);
        *(ushort4*)(p + tid * 8 + 4) = make_ushort4(ob[4], ob[5], ob[6], ob[7]);
    } else {
        int t = bid - 8192;
        int z = t >> 11;                 // batch
        int rest = t & 2047;             // 32 col-tiles x 64 row-tiles
        int c0 = (rest & 31) * 32;
        int r0 = (rest >> 5) * 32;
        long long zs = (long long)z * 2048 * 1024;
        int tx = tid & 31, ty = tid >> 5;
#pragma unroll
        for (int j = 0; j < 32; j += 8)
            tile[ty + j][tx] = v[zs + (long long)(r0 + ty + j) * 1024 + c0 + tx];
        __syncthreads();
#pragma unroll
        for (int j = 0; j < 32; j += 8)
            vT[zs + (long long)(c0 + ty + j) * 2048 + r0 + tx] =
                tile[tx][ty + j];
    }
}

// ---------------------------------------------------------------------------
extern "C" void kernel_launch(void* const* d_in, const int* in_sizes, int n_in,
                              void* d_out, int out_size, void* d_ws,
                              size_t ws_size, hipStream_t stream) {
    const float* x  = (const float*)d_in[0];
    const float* Wk = (const float*)d_in[1];
    const float* bk = (const float*)d_in[2];
    const float* Wq = (const float*)d_in[3];
    const float* bq = (const float*)d_in[4];
    const float* Wv = (const float*)d_in[5];
    const float* bv = (const float*)d_in[6];
    float* out = (float*)d_out;

    const int Bb = 4, Ns = 2048, E = 1024, Aa = 1024;
    const int M = Bb * Ns;  // 8192

    char* p = (char*)d_ws;
    auto alloc = [&](size_t bytes) {
        char* r = p;
        p += (bytes + 255) & ~(size_t)255;
        return r;
    };
    const size_t MA = (size_t)M * Aa;          // 8.39M elems
    unsigned short* x16 = (unsigned short*)alloc(MA * 2);
    unsigned short* WT  = (unsigned short*)alloc((size_t)3 * E * Aa * 2);
    // k16,q16,v16 MUST be contiguous (segmented epilogue): MA*2 is a
    // multiple of 256, so alloc() inserts no padding.
    unsigned short* k16 = (unsigned short*)alloc(MA * 2);
    unsigned short* q16 = (unsigned short*)alloc(MA * 2);
    unsigned short* v16 = (unsigned short*)alloc(MA * 2);
    unsigned short* vT  = (unsigned short*)alloc(MA * 2);
    unsigned short* attn = (unsigned short*)alloc((size_t)M * Ns * 2);
    float* bias3 = (float*)alloc(3072 * 4);
    float* scores = (float*)alloc((size_t)Bb * Ns * Ns * 4);

    // 1. prep: x->fp16, W^T x3, bias concat (one dispatch)
    prep<<<11276, 256, 0, stream>>>(x, Wk, Wq, Wv, bk, bq, bv, x16, WT, bias3);

    // 2. fused projections: [k|q|v] = x16 @ [Wk|Wq|Wv]^T + bias3
    //    grid 24 x 64 = 1536 blocks (%256 == 0, no tail round)
    gemm_nt<128><<<dim3(3 * Aa / 128, M / 128, 1), 256, 0, stream>>>(
        x16, WT, bias3, nullptr, k16, 2, M, 3 * Aa, E, 0, 0, (long long)MA);

    // 3. scores[b,n,m] = k[b,n,:] . q[b,m,:]   (batched NT fp16, fp32 out)
    //    grid 16 x 16 x 4 = 1024 blocks
    gemm_nt<128><<<dim3(Ns / 128, Ns / 128, Bb), 256, 0, stream>>>(
        k16, q16, nullptr, scores, nullptr, 0, Ns, Ns, Aa,
        (long long)Ns * Aa, (long long)Ns * Aa, (long long)Ns * Ns);

    // 4. softmax rows -> fp16 attn; v -> v^T (one dispatch)
    softmax_vT<<<16384, 256, 0, stream>>>(scores, attn, v16, vT);

    // 5. out[b,n,a] = sum_m attn[b,n,m] * vT[b,a,m]   grid 512 blocks
    gemm_nt<128><<<dim3(Aa / 128, Ns / 128, Bb), 256, 0, stream>>>(
        attn, vT, nullptr, out, nullptr, 0, Ns, Aa, Ns,
        (long long)Ns * Ns, (long long)Aa * Ns, (long long)Ns * Aa);
}